// Round 1
// baseline (153.949 us; speedup 1.0000x reference)
//
#include <hip/hip_runtime.h>

// FSAF target assignment, MI355X — sparse-write version.
// All zero-valued outputs are produced by one hipMemsetAsync over the whole
// output (runs as the rocclr fill kernel at ~6.5 TB/s). The kernel writes only
// nonzero values: cls_m=1.0 (dense-ish), and reg_t/reg_m/one-hot at the ~15k
// positive pixels. Arithmetic identical to the previous verified kernel.
//
// Output layout (f32, concatenated): cls_t (16,21824,80) | cls_m (16,21824) |
// num_pos (16,) | reg_t (16,21824,4) | reg_m (16,21824)

#define NPIX      21824
#define NBOX      64
#define BATCH     16
#define BIG_AREA  10000000.0f

#define CLSM_OFF  27934720          // 16*21824*80
#define NUMP_OFF  28283904          // CLSM_OFF + 16*21824
#define REGT_OFF  28283920          // NUMP_OFF + 16
#define REGM_OFF  29680656          // REGT_OFF + 16*21824*4
#define OUT_FLOATS 30029840         // REGM_OFF + 16*21824
// REGT_OFF/4 = 7070980  (float4-aligned)

__device__ __forceinline__ void prop_box(float x1, float y1, float x2, float y2,
                                         float a, float fwf,
                                         int& ox1, int& oy1, int& ox2, int& oy2) {
    // Match numpy exactly: block FMA contraction with _rn intrinsics.
    float w = __fsub_rn(x2, x1);
    float h = __fsub_rn(y2, y1);
    float nx1 = floorf(__fadd_rn(x1, __fmul_rn(a, w)));
    float ny1 = floorf(__fadd_rn(y1, __fmul_rn(a, h)));
    float nx2 = ceilf(__fsub_rn(x2, __fmul_rn(a, w)));
    float ny2 = ceilf(__fsub_rn(y2, __fmul_rn(a, h)));
    nx2 = fminf(fmaxf(fmaxf(nx2, __fadd_rn(nx1, 1.0f)), 0.0f), fwf);
    ny2 = fminf(fmaxf(fmaxf(ny2, __fadd_rn(ny1, 1.0f)), 0.0f), fwf);
    nx1 = fminf(fmaxf(nx1, 0.0f), fwf - 1.0f);
    ny1 = fminf(fmaxf(ny1, 0.0f), fwf - 1.0f);
    ox1 = (int)nx1; oy1 = (int)ny1; ox2 = (int)nx2; oy2 = (int)ny2;
}

__global__ __launch_bounds__(256) void fsaf_kernel(const int* __restrict__ levels,
                                                   const float* __restrict__ gt,
                                                   float* __restrict__ out) {
    const int img = blockIdx.y;
    const int bx  = blockIdx.x;          // 0..85 — each block inside one level
    const int tid = threadIdx.x;

    int level, loff, fwl;
    if      (bx < 64) { level = 0; loff = 0;     fwl = 7; }   // 128x128
    else if (bx < 80) { level = 1; loff = 16384; fwl = 6; }   // 64x64
    else if (bx < 84) { level = 2; loff = 20480; fwl = 5; }   // 32x32
    else if (bx == 84){ level = 3; loff = 21504; fwl = 4; }   // 16x16
    else              { level = 4; loff = 21760; fwl = 3; }   // 8x8 (64 px)

    const int    fw      = 1 << fwl;
    const float  stride  = (float)(8 << level);
    const int    pixBase = bx << 8;
    const int    numPix  = min(256, NPIX - pixBase);
    const size_t imgBase = (size_t)img * NPIX;

    // ---- 1. wave-0: per-box prop rects + tile-row intersection compaction.
    __shared__ int4   s_pos[NBOX];     // compacted pos rect (x1,y1,x2,y2)
    __shared__ int4   s_ign[NBOX];     // compacted ignore rect (superset of pos)
    __shared__ float  s_area[NBOX];
    __shared__ float4 s_box[NBOX];     // image-coord box for regr target
    __shared__ int    s_lab[NBOX];
    __shared__ int    s_cnt;

    if (tid < NBOX) {
        const float* g = gt + (size_t)(img * NBOX + tid) * 5;
        float b0 = g[0], b1 = g[1], b2 = g[2], b3 = g[3];
        int   lab   = (int)g[4];
        bool  valid = (levels[img * NBOX + tid] == level);

        const float inv = 1.0f / stride;              // pow2 -> exact
        float px1 = b0 * inv, py1 = b1 * inv, px2 = b2 * inv, py2 = b3 * inv;
        const float fwf = (float)fw;

        int pa, pb, pc, pd, ia, ib, ic, id;
        prop_box(px1, py1, px2, py2, 0.4f,  fwf, pa, pb, pc, pd);  // POS_SCALE=0.2
        prop_box(px1, py1, px2, py2, 0.25f, fwf, ia, ib, ic, id);  // IGNORE_SCALE=0.5

        // tile = full-width rows [y0, yEnd); ignore-rect row test (pos ⊆ ign)
        int y0   = (pixBase - loff) >> fwl;
        int yEnd = y0 + (numPix >> fwl);
        bool hit = valid && (ib < yEnd) && (id > y0);

        unsigned long long m = __ballot(hit);         // wave 0 only
        if (hit) {
            int idx = __popcll(m & ((1ull << tid) - 1ull));  // order-preserving
            s_pos[idx]  = make_int4(pa, pb, pc, pd);
            s_ign[idx]  = make_int4(ia, ib, ic, id);
            s_area[idx] = (b2 - b0) * (b3 - b1);      // sub,sub,mul — no FMA risk
            s_box[idx]  = make_float4(b0, b1, b2, b3);
            s_lab[idx]  = lab;
        }
        if (tid == 0) s_cnt = __popcll(m);
    }
    __syncthreads();

    // ---- 2. per-pixel scan over the (short) compacted list.
    const int  p      = pixBase + tid;
    const bool active = tid < numPix;
    const int  local  = p - loff;
    const int  y      = local >> fwl;
    const int  x      = local & (fw - 1);

    float best   = BIG_AREA;
    int   chosen = 0;
    bool  anyIgn = false;
    const int cnt = s_cnt;
    for (int n = 0; n < cnt; ++n) {
        int4 ig = s_ign[n];
        bool ing = (y >= ig.y) & (y < ig.w) & (x >= ig.x) & (x < ig.z);
        anyIgn |= ing;
        int4 ps = s_pos[n];
        bool inp = (y >= ps.y) & (y < ps.w) & (x >= ps.x) & (x < ps.z);
        float am = inp ? s_area[n] : BIG_AREA;
        bool better = am < best;                      // strict '<' = first-min
        best   = better ? am : best;
        chosen = better ? n  : chosen;
    }
    const bool anyPos = best < BIG_AREA;

    if (active) {
        // cls_m: 1.0 where (pos or not-ignored); 0.0 elsewhere comes from memset.
        if (anyPos || !anyIgn) out[CLSM_OFF + imgBase + p] = 1.0f;

        if (anyPos) {
            // reg_m = 1.0 only at positive pixels (memset covers the zeros)
            out[REGM_OFF + imgBase + p] = 1.0f;

            float4 cb = s_box[chosen];
            float sx = ((float)x + 0.5f) * stride;    // exact
            float sy = ((float)y + 0.5f) * stride;
            float4 rt;
            rt.x = (sx - cb.x) * 0.25f;
            rt.y = (sy - cb.y) * 0.25f;
            rt.z = (cb.z - sx) * 0.25f;
            rt.w = (cb.w - sy) * 0.25f;
            ((float4*)out)[(size_t)REGT_OFF / 4 + imgBase + p] = rt;

            // sparse one-hot scatter into the memset-zeroed cls_t region
            out[(imgBase + p) * 80 + s_lab[chosen]] = 1.0f;
        }
    }

    // ---- 3. num_pos: per-wave ballot + one float atomic per wave.
    unsigned long long bal = __ballot(active && anyPos);
    if ((tid & 63) == 0) {
        int c = __popcll(bal);
        if (c) atomicAdd(out + NUMP_OFF + img, (float)c);
    }
}

extern "C" void kernel_launch(void* const* d_in, const int* in_sizes, int n_in,
                              void* d_out, int out_size, void* d_ws, size_t ws_size,
                              hipStream_t stream) {
    const int*   levels = (const int*)d_in[0];    // (16,64) int32
    const float* gt     = (const float*)d_in[1];  // (16,64,5) f32
    float*       out    = (float*)d_out;

    // One bulk zero of the entire output (cls_t, cls_m, num_pos, reg_t, reg_m).
    // Dispatches the rocclr fill kernel — measured 6.5 TB/s on this buffer.
    hipMemsetAsync(d_out, 0, (size_t)OUT_FLOATS * sizeof(float), stream);

    dim3 grid(86, BATCH);
    fsaf_kernel<<<grid, 256, 0, stream>>>(levels, gt, out);
}

// Round 2
// 139.694 us; speedup vs baseline: 1.1021x; 1.1021x over previous
//
#include <hip/hip_runtime.h>

// FSAF target assignment, MI355X — fused-fill, compute-first ordering.
// R1 post-mortem: bulk memset regressed (+13.6us); round-0's fused fill was
// already ~5.7 TB/s. This version removes round-0's only structural stall:
// the mid-kernel barrier that drained 80KB of fill stores before the one-hot
// scatter. Now: compute -> (small barrier) -> streaming fill with the one-hot
// constructed inline. No barrier after the bulk stores.
//
// Output layout (f32, concatenated): cls_t (16,21824,80) | cls_m (16,21824) |
// num_pos (16,) | reg_t (16,21824,4) | reg_m (16,21824)

#define NPIX      21824
#define NBOX      64
#define BATCH     16
#define BIG_AREA  10000000.0f

#define CLSM_OFF  27934720          // 16*21824*80
#define NUMP_OFF  28283904          // CLSM_OFF + 16*21824
#define REGT_OFF  28283920          // NUMP_OFF + 16
#define REGM_OFF  29680656          // REGT_OFF + 16*21824*4
// REGT_OFF/4 = 7070980  (float4-aligned)

__device__ __forceinline__ void prop_box(float x1, float y1, float x2, float y2,
                                         float a, float fwf,
                                         int& ox1, int& oy1, int& ox2, int& oy2) {
    // Match numpy exactly: block FMA contraction with _rn intrinsics.
    float w = __fsub_rn(x2, x1);
    float h = __fsub_rn(y2, y1);
    float nx1 = floorf(__fadd_rn(x1, __fmul_rn(a, w)));
    float ny1 = floorf(__fadd_rn(y1, __fmul_rn(a, h)));
    float nx2 = ceilf(__fsub_rn(x2, __fmul_rn(a, w)));
    float ny2 = ceilf(__fsub_rn(y2, __fmul_rn(a, h)));
    nx2 = fminf(fmaxf(fmaxf(nx2, __fadd_rn(nx1, 1.0f)), 0.0f), fwf);
    ny2 = fminf(fmaxf(fmaxf(ny2, __fadd_rn(ny1, 1.0f)), 0.0f), fwf);
    nx1 = fminf(fmaxf(nx1, 0.0f), fwf - 1.0f);
    ny1 = fminf(fmaxf(ny1, 0.0f), fwf - 1.0f);
    ox1 = (int)nx1; oy1 = (int)ny1; ox2 = (int)nx2; oy2 = (int)ny2;
}

__global__ __launch_bounds__(256) void fsaf_kernel(const int* __restrict__ levels,
                                                   const float* __restrict__ gt,
                                                   float* __restrict__ out) {
    const int img = blockIdx.y;
    const int bx  = blockIdx.x;          // 0..85 — each block inside one level
    const int tid = threadIdx.x;

    int level, loff, fwl;
    if      (bx < 64) { level = 0; loff = 0;     fwl = 7; }   // 128x128
    else if (bx < 80) { level = 1; loff = 16384; fwl = 6; }   // 64x64
    else if (bx < 84) { level = 2; loff = 20480; fwl = 5; }   // 32x32
    else if (bx == 84){ level = 3; loff = 21504; fwl = 4; }   // 16x16
    else              { level = 4; loff = 21760; fwl = 3; }   // 8x8 (64 px)

    const int    fw      = 1 << fwl;
    const float  stride  = (float)(8 << level);
    const int    pixBase = bx << 8;
    const int    numPix  = min(256, NPIX - pixBase);
    const size_t imgBase = (size_t)img * NPIX;

    // ---- 1. wave-0: per-box prop rects + tile-row intersection compaction.
    __shared__ int4   s_pos[NBOX];     // compacted pos rect (x1,y1,x2,y2)
    __shared__ int4   s_ign[NBOX];     // compacted ignore rect (superset of pos)
    __shared__ float  s_area[NBOX];
    __shared__ float4 s_box[NBOX];     // image-coord box for regr target
    __shared__ int    s_lab[NBOX];
    __shared__ int    s_cnt;
    __shared__ int    s_pix[256];      // per-pixel: chosen label, or -1

    if (tid < NBOX) {
        const float* g = gt + (size_t)(img * NBOX + tid) * 5;
        float b0 = g[0], b1 = g[1], b2 = g[2], b3 = g[3];
        int   lab   = (int)g[4];
        bool  valid = (levels[img * NBOX + tid] == level);

        const float inv = 1.0f / stride;              // pow2 -> exact
        float px1 = b0 * inv, py1 = b1 * inv, px2 = b2 * inv, py2 = b3 * inv;
        const float fwf = (float)fw;

        int pa, pb, pc, pd, ia, ib, ic, id;
        prop_box(px1, py1, px2, py2, 0.4f,  fwf, pa, pb, pc, pd);  // POS_SCALE=0.2
        prop_box(px1, py1, px2, py2, 0.25f, fwf, ia, ib, ic, id);  // IGNORE_SCALE=0.5

        // tile = full-width rows [y0, yEnd); ignore-rect row test (pos ⊆ ign)
        int y0   = (pixBase - loff) >> fwl;
        int yEnd = y0 + (numPix >> fwl);
        bool hit = valid && (ib < yEnd) && (id > y0);

        unsigned long long m = __ballot(hit);         // wave 0 only
        if (hit) {
            int idx = __popcll(m & ((1ull << tid) - 1ull));  // order-preserving
            s_pos[idx]  = make_int4(pa, pb, pc, pd);
            s_ign[idx]  = make_int4(ia, ib, ic, id);
            s_area[idx] = (b2 - b0) * (b3 - b1);      // sub,sub,mul — no FMA risk
            s_box[idx]  = make_float4(b0, b1, b2, b3);
            s_lab[idx]  = lab;
        }
        if (tid == 0) s_cnt = __popcll(m);
    }
    __syncthreads();

    // ---- 2. per-pixel scan over the (short) compacted list.
    const int  p      = pixBase + tid;
    const bool active = tid < numPix;
    const int  local  = p - loff;
    const int  y      = local >> fwl;
    const int  x      = local & (fw - 1);

    float best   = BIG_AREA;
    int   chosen = 0;
    bool  anyIgn = false;
    const int cnt = s_cnt;
    for (int n = 0; n < cnt; ++n) {
        int4 ig = s_ign[n];
        bool ing = (y >= ig.y) & (y < ig.w) & (x >= ig.x) & (x < ig.z);
        anyIgn |= ing;
        int4 ps = s_pos[n];
        bool inp = (y >= ps.y) & (y < ps.w) & (x >= ps.x) & (x < ps.z);
        float am = inp ? s_area[n] : BIG_AREA;
        bool better = am < best;                      // strict '<' = first-min
        best   = better ? am : best;
        chosen = better ? n  : chosen;
    }
    const bool anyPos = best < BIG_AREA;

    const float4 z4 = {0.f, 0.f, 0.f, 0.f};
    if (active) {
        out[CLSM_OFF + imgBase + p] = (anyPos || !anyIgn) ? 1.0f : 0.0f;
        out[REGM_OFF + imgBase + p] = anyPos ? 1.0f : 0.0f;

        float4 rt = z4;
        if (anyPos) {
            float4 cb = s_box[chosen];
            float sx = ((float)x + 0.5f) * stride;    // exact
            float sy = ((float)y + 0.5f) * stride;
            rt.x = (sx - cb.x) * 0.25f;
            rt.y = (sy - cb.y) * 0.25f;
            rt.z = (cb.z - sx) * 0.25f;
            rt.w = (cb.w - sy) * 0.25f;
        }
        ((float4*)out)[(size_t)REGT_OFF / 4 + imgBase + p] = rt;
    }
    // per-pixel one-hot descriptor for the fill pass (label 0..79, or -1)
    s_pix[tid] = (active && anyPos) ? s_lab[chosen] : -1;

    // ---- 3. num_pos: per-wave ballot + one float atomic per wave.
    unsigned long long bal = __ballot(active && anyPos);
    if ((tid & 63) == 0) {
        int c = __popcll(bal);
        if (c) atomicAdd(out + NUMP_OFF + img, (float)c);
    }

    __syncthreads();   // s_pix visibility; drains only the 3 small stores above

    // ---- 4. cls_t streaming write, one-hot constructed inline.
    // Coalesced dwordx4 stream; last phase of the kernel -> no barrier after,
    // waves retire with stores in flight (no vmcnt(0) drain stall).
    float4* cls4 = (float4*)out;
    const size_t base4  = (imgBase + (size_t)pixBase) * 20;
    const int    total4 = numPix * 20;
    for (int f = tid; f < total4; f += 256) {
        const int q   = f / 20;            // tile-local pixel (magic-mul)
        const int c   = f - q * 20;        // float4 chunk 0..19
        const int lab = s_pix[q];          // broadcast-ish LDS read
        const int b   = c << 2;
        float4 v;
        v.x = (lab == b    ) ? 1.0f : 0.0f;   // lab==-1 never matches
        v.y = (lab == b + 1) ? 1.0f : 0.0f;
        v.z = (lab == b + 2) ? 1.0f : 0.0f;
        v.w = (lab == b + 3) ? 1.0f : 0.0f;
        cls4[base4 + f] = v;
    }
}

extern "C" void kernel_launch(void* const* d_in, const int* in_sizes, int n_in,
                              void* d_out, int out_size, void* d_ws, size_t ws_size,
                              hipStream_t stream) {
    const int*   levels = (const int*)d_in[0];    // (16,64) int32
    const float* gt     = (const float*)d_in[1];  // (16,64,5) f32
    float*       out    = (float*)d_out;

    // zero the 16 num_pos accumulators (graph-capture-safe)
    hipMemsetAsync((char*)d_out + (size_t)NUMP_OFF * sizeof(float), 0,
                   BATCH * sizeof(float), stream);

    dim3 grid(86, BATCH);
    fsaf_kernel<<<grid, 256, 0, stream>>>(levels, gt, out);
}